// Round 28
// baseline (174.646 us; speedup 1.0000x reference)
//
#include <hip/hip_runtime.h>
#include <hip/hip_bf16.h>

#define HW 16384
#define NC 256
#define NO 64
#define NPM 1048576          // floats per (b, modality)
#define EPS_IN 1e-5f
#define DBLK 1024            // k_dots blocks.x
#define WIN 1024             // floats per modality per window
#define SPX 128              // pixels per k_gemm block window
#define NPR 16               // channel pairs per 32-ch chunk
#define PRW 264              // dwords per pair-row: 2*128 + 8 pad

typedef float f32x4 __attribute__((ext_vector_type(4)));
typedef short bhalf8 __attribute__((ext_vector_type(8)));

static __device__ __forceinline__ short f2bf(float f){
  __bf16 h = (__bf16)f;
  return __builtin_bit_cast(short, h);
}

// ws float layout: [256,320) probs[b][m] ; [8192, +163840) dots partials ;
//                  [180224, +262144) gemm stats part[b][bx128][o][2]
//                  (all fully overwritten every call -> no zeroing needed)

// Pass 1: Gram partials (proven ~50us / 5.4TB/s structure, untouched).
__global__ void k_dots(const float* __restrict__ x, float* __restrict__ partials){
  __shared__ float lds[4][WIN];
  __shared__ float red[4][16];
  const int b = blockIdx.y, bx = blockIdx.x;
  const int tid = threadIdx.x;
  const int w = tid >> 6, lane = tid & 63;
  const int wi = (bx + b*67) & (DBLK-1);
  const float* src = x + (size_t)b*4*NPM + (size_t)w*NPM + (size_t)wi*WIN + lane*4;

  #pragma unroll
  for (int li=0; li<4; li++){
    __builtin_amdgcn_global_load_lds(
        (const __attribute__((address_space(1))) void*)(src + li*256),
        (__attribute__((address_space(3))) void*)&lds[w][li*256],
        16, 0, 0);
  }
  __syncthreads();

  float4 vv[4];
  #pragma unroll
  for (int m=0;m<4;m++) vv[m] = *(const float4*)&lds[m][tid*4];
  float acc[10];
  int k=0;
  #pragma unroll
  for (int i=0;i<4;i++)
    #pragma unroll
    for (int j=i;j<4;j++,k++)
      acc[k] = vv[i].x*vv[j].x + vv[i].y*vv[j].y + vv[i].z*vv[j].z + vv[i].w*vv[j].w;

  #pragma unroll
  for (int kk=0;kk<10;kk++){
    float s = acc[kk];
    #pragma unroll
    for (int off=1; off<64; off<<=1) s += __shfl_xor(s, off, 64);
    acc[kk]=s;
  }
  if (lane==0){
    #pragma unroll
    for (int kk=0;kk<10;kk++) red[w][kk] = acc[kk];
  }
  __syncthreads();
  if (tid<10){
    float s = red[0][tid] + red[1][tid] + red[2][tid] + red[3][tid];
    partials[((size_t)b*DBLK + bx)*10 + tid] = s;
  }
}

__global__ void k_attn(const float* __restrict__ partials, float* __restrict__ probs){
  __shared__ float red[4][16];
  int b = blockIdx.x, tid = threadIdx.x;       // 256 threads
  int w = tid>>6, lane = tid&63;
  float a[10];
  #pragma unroll
  for (int kk=0;kk<10;kk++) a[kk]=0.f;
  #pragma unroll
  for (int r=0;r<DBLK/256;r++){
    const float* p = partials + ((size_t)b*DBLK + r*256 + tid)*10;
    #pragma unroll
    for (int kk=0;kk<10;kk++) a[kk]+=p[kk];
  }
  #pragma unroll
  for (int kk=0;kk<10;kk++){
    float s=a[kk];
    #pragma unroll
    for (int off=1;off<64;off<<=1) s+=__shfl_xor(s,off,64);
    a[kk]=s;
  }
  if (lane==0){
    #pragma unroll
    for (int kk=0;kk<10;kk++) red[w][kk]=a[kk];
  }
  __syncthreads();
  if (tid==0){
    float d[10];
    #pragma unroll
    for (int kk=0;kk<10;kk++) d[kk]=red[0][kk]+red[1][kk]+red[2][kk]+red[3][kk];
    float D[4][4];
    int k2=0;
    #pragma unroll
    for (int i=0;i<4;i++)
      #pragma unroll
      for (int j=i;j<4;j++,k2++){ D[i][j]=d[k2]; D[j][i]=d[k2]; }
    float nrm[4];
    #pragma unroll
    for (int m=0;m<4;m++) nrm[m]=fmaxf(sqrtf(D[m][m]),1e-8f);
    float sc[4];
    #pragma unroll
    for (int i=0;i<4;i++){
      float s=0.f;
      #pragma unroll
      for (int j=0;j<4;j++) s += D[i][j]/(nrm[i]*nrm[j]);
      sc[i] = -(s-1.0f);
    }
    float mx = fmaxf(fmaxf(sc[0],sc[1]), fmaxf(sc[2],sc[3]));
    float e[4], se=0.f;
    #pragma unroll
    for (int m=0;m<4;m++){ e[m]=expf(sc[m]-mx); se+=e[m]; }
    #pragma unroll
    for (int m=0;m<4;m++) probs[b*4+m]=e[m]/se;
  }
}

// GEMM: atomic-free R27 skeleton re-geometried for 4 blocks/CU (vs 2):
// 128-thr blocks, SPX=128, pair-row LDS buf[2][16][264] = 33.8KB dbuf.
// 2048 independent blocks double block-level stage/compute overlap.
// Pair-row: 1KB gload_lds = 2 channel rows; 8-dword pad keeps 2-way banks.
__launch_bounds__(128, 2)
__global__ void k_gemm(const float* __restrict__ x, const float* __restrict__ w,
                       const float* __restrict__ ws, float* __restrict__ y,
                       float* __restrict__ part){
  __shared__ float buf[2][NPR][PRW];   // 33,792 B
  const int b   = blockIdx.y;
  const int pw  = blockIdx.x * SPX;
  const int tid = threadIdx.x;
  const int wid = tid >> 6;      // 2 waves: row half (32 rows each)
  const int lane = tid & 63;
  const int l15 = lane & 15;
  const int lg  = lane >> 4;

  const float* probs = ws + 256 + b*4;
  float pm[4] = {probs[0], probs[1], probs[2], probs[3]};
  bhalf8 afrag[2][8];
  const float4* w4 = reinterpret_cast<const float4*>(w);
  #pragma unroll
  for (int rt=0; rt<2; rt++){
    int row = wid*32 + rt*16 + l15;
    #pragma unroll
    for (int ks=0; ks<8; ks++){
      float s = pm[ks>>1];
      float4 a0 = w4[row*64 + ks*8 + lg];
      float4 a1 = w4[row*64 + ks*8 + lg + 4];
      bhalf8 f;
      f[0]=f2bf(a0.x*s); f[1]=f2bf(a0.y*s); f[2]=f2bf(a0.z*s); f[3]=f2bf(a0.w*s);
      f[4]=f2bf(a1.x*s); f[5]=f2bf(a1.y*s); f[6]=f2bf(a1.z*s); f[7]=f2bf(a1.w*s);
      afrag[rt][ks] = f;
    }
  }

  const float* xb = x + (size_t)b*NC*HW + pw;

  // stage chunk cc (32 ch x 128 px = 16KB): 8 instrs/wave, each 1KB = one
  // channel PAIR (lanes 0-31 -> even row, 32-63 -> odd row), dest linear.
  auto STAGE = [&](int cc, int cur){
    #pragma unroll
    for (int j=0; j<8; j++){
      int pr = wid*8 + j;
      const float* src = xb + (size_t)(cc*32 + pr*2 + (lane>>5))*HW + (lane&31)*4;
      __builtin_amdgcn_global_load_lds(
          (const __attribute__((address_space(1))) void*)src,
          (__attribute__((address_space(3))) void*)&buf[cur][pr][0],
          16, 0, 0);
    }
  };

  f32x4 acc[2][8];
  #pragma unroll
  for (int rt=0; rt<2; rt++)
    #pragma unroll
    for (int pt=0; pt<8; pt++) acc[rt][pt] = (f32x4){0.f,0.f,0.f,0.f};

  STAGE(0, 0);
  int cur = 0;
  #pragma unroll 1
  for (int cc=0; cc<8; cc++){
    if (cc < 7){
      STAGE(cc+1, cur^1);
      asm volatile("s_waitcnt vmcnt(8)" ::: "memory");
    } else {
      asm volatile("s_waitcnt vmcnt(0)" ::: "memory");
    }
    __builtin_amdgcn_s_barrier();        // all waves' chunk-cc writes done
    __builtin_amdgcn_sched_barrier(0);

    const float (*bp)[PRW] = buf[cur];
    #pragma unroll
    for (int pt=0; pt<8; pt++){
      int px = pt*16 + l15;
      bhalf8 bfr;
      #pragma unroll
      for (int eh=0; eh<2; eh++)
        #pragma unroll
        for (int el=0; el<4; el++){
          int c = lg*4 + el + eh*16;            // 0..31 within chunk
          bfr[eh*4+el] = f2bf(bp[c>>1][(c&1)*128 + px]);
        }
      #pragma unroll
      for (int rt=0; rt<2; rt++)
        acc[rt][pt] = __builtin_amdgcn_mfma_f32_16x16x32_bf16(afrag[rt][cc], bfr, acc[rt][pt], 0, 0, 0);
    }

    __builtin_amdgcn_sched_barrier(0);
    __builtin_amdgcn_s_barrier();        // reads done -> buf[cur] reusable
    cur ^= 1;
  }

  // epilogue: NT y write + per-block stats stores (no atomics)
  float sacc[2][4] = {{0}}, qacc[2][4] = {{0}};
  #pragma unroll
  for (int rt=0; rt<2; rt++){
    #pragma unroll
    for (int pt=0; pt<8; pt++){
      size_t ybase = ((size_t)(b*NO + wid*32 + rt*16 + lg*4))*HW + pw + pt*16 + l15;
      #pragma unroll
      for (int r=0; r<4; r++){
        float v = acc[rt][pt][r];
        __builtin_nontemporal_store(v, &y[ybase + (size_t)r*HW]);
        sacc[rt][r] += v;
        qacc[rt][r] += v*v;
      }
    }
  }
  float* sp = part + ((size_t)(b*128 + blockIdx.x))*NO*2;  // [o][2]: s,q
  #pragma unroll
  for (int rt=0; rt<2; rt++){
    #pragma unroll
    for (int r=0; r<4; r++){
      float s = sacc[rt][r], q = qacc[rt][r];
      #pragma unroll
      for (int off=1; off<16; off<<=1){
        s += __shfl_xor(s, off, 64);
        q += __shfl_xor(q, off, 64);
      }
      if (l15 == 0){
        int o = wid*32 + rt*16 + lg*4 + r;
        sp[o*2]     = s;
        sp[o*2 + 1] = q;
      }
    }
  }
}

__global__ void k_norm(float* __restrict__ y, const float* __restrict__ part){
  __shared__ float red2[2][2];
  const int bo = blockIdx.x, b = bo >> 6, o = bo & 63;
  const int tid = threadIdx.x;
  float s = 0.f, q = 0.f;
  if (tid < 128){
    const float* p = part + (((size_t)(b*128 + tid))*NO + o)*2;
    s = p[0]; q = p[1];
  }
  #pragma unroll
  for (int off=1; off<64; off<<=1){
    s += __shfl_xor(s, off, 64);
    q += __shfl_xor(q, off, 64);
  }
  if (tid < 128 && (tid & 63) == 0){ red2[tid>>6][0] = s; red2[tid>>6][1] = q; }
  __syncthreads();
  float S = red2[0][0] + red2[1][0];
  float Q = red2[0][1] + red2[1][1];
  float mean = S * (1.f/HW);
  float var  = Q * (1.f/HW) - mean*mean;
  float inv  = rsqrtf(var + EPS_IN);
  f32x4* yp = reinterpret_cast<f32x4*>(y) + (size_t)bo*(HW/4);
  #pragma unroll 4
  for (int i = tid; i < HW/4; i += 256){
    f32x4 v = yp[i];
    v.x = fmaxf((v.x-mean)*inv, 0.f);
    v.y = fmaxf((v.y-mean)*inv, 0.f);
    v.z = fmaxf((v.z-mean)*inv, 0.f);
    v.w = fmaxf((v.w-mean)*inv, 0.f);
    __builtin_nontemporal_store(v, &yp[i]);
  }
}

extern "C" void kernel_launch(void* const* d_in, const int* in_sizes, int n_in,
                              void* d_out, int out_size, void* d_ws, size_t ws_size,
                              hipStream_t stream){
  const float* x = (const float*)d_in[0];
  const float* w = (const float*)d_in[1];
  float* out = (float*)d_out;
  float* ws  = (float*)d_ws;
  float* partials = ws + 8192;
  float* probs    = ws + 256;
  float* part     = ws + 180224;

  k_dots<<<dim3(DBLK,16),    dim3(256), 0, stream>>>(x, partials);
  k_attn<<<dim3(16),         dim3(256), 0, stream>>>(partials, probs);
  k_gemm<<<dim3(HW/SPX,16),  dim3(128), 0, stream>>>(x, w, ws, out, part);
  k_norm<<<dim3(1024),       dim3(256), 0, stream>>>(out, part);
}

// Round 29
// 174.419 us; speedup vs baseline: 1.0013x; 1.0013x over previous
//
#include <hip/hip_runtime.h>
#include <hip/hip_bf16.h>

#define HW 16384
#define NC 256
#define NO 64
#define NPM 1048576          // floats per (b, modality)
#define EPS_IN 1e-5f
#define DBLK 1024            // k_dots blocks.x
#define WIN 1024             // floats per modality per window
#define SPX 256              // pixels per k_gemm block window (R27 geometry)
#define SCH 32               // channels per staged chunk
#define NCHK 8               // 256 / SCH
#define PAD 4                // floats of row padding in LDS

typedef float f32x4 __attribute__((ext_vector_type(4)));
typedef short bhalf8 __attribute__((ext_vector_type(8)));

static __device__ __forceinline__ short f2bf(float f){
  __bf16 h = (__bf16)f;
  return __builtin_bit_cast(short, h);
}

// ws float layout: [256,320) probs[b][m] ; [8192, +163840) dots partials ;
//                  [180224, +262144) gemm stats part[b][bx][o][4]
//                  (all fully overwritten every call -> no zeroing needed)

// Pass 1: Gram partials (proven ~50us / 5.4TB/s structure, untouched).
__global__ void k_dots(const float* __restrict__ x, float* __restrict__ partials){
  __shared__ float lds[4][WIN];
  __shared__ float red[4][16];
  const int b = blockIdx.y, bx = blockIdx.x;
  const int tid = threadIdx.x;
  const int w = tid >> 6, lane = tid & 63;
  const int wi = (bx + b*67) & (DBLK-1);
  const float* src = x + (size_t)b*4*NPM + (size_t)w*NPM + (size_t)wi*WIN + lane*4;

  #pragma unroll
  for (int li=0; li<4; li++){
    __builtin_amdgcn_global_load_lds(
        (const __attribute__((address_space(1))) void*)(src + li*256),
        (__attribute__((address_space(3))) void*)&lds[w][li*256],
        16, 0, 0);
  }
  __syncthreads();

  float4 vv[4];
  #pragma unroll
  for (int m=0;m<4;m++) vv[m] = *(const float4*)&lds[m][tid*4];
  float acc[10];
  int k=0;
  #pragma unroll
  for (int i=0;i<4;i++)
    #pragma unroll
    for (int j=i;j<4;j++,k++)
      acc[k] = vv[i].x*vv[j].x + vv[i].y*vv[j].y + vv[i].z*vv[j].z + vv[i].w*vv[j].w;

  #pragma unroll
  for (int kk=0;kk<10;kk++){
    float s = acc[kk];
    #pragma unroll
    for (int off=1; off<64; off<<=1) s += __shfl_xor(s, off, 64);
    acc[kk]=s;
  }
  if (lane==0){
    #pragma unroll
    for (int kk=0;kk<10;kk++) red[w][kk] = acc[kk];
  }
  __syncthreads();
  if (tid<10){
    float s = red[0][tid] + red[1][tid] + red[2][tid] + red[3][tid];
    partials[((size_t)b*DBLK + bx)*10 + tid] = s;
  }
}

__global__ void k_attn(const float* __restrict__ partials, float* __restrict__ probs){
  __shared__ float red[4][16];
  int b = blockIdx.x, tid = threadIdx.x;       // 256 threads
  int w = tid>>6, lane = tid&63;
  float a[10];
  #pragma unroll
  for (int kk=0;kk<10;kk++) a[kk]=0.f;
  #pragma unroll
  for (int r=0;r<DBLK/256;r++){
    const float* p = partials + ((size_t)b*DBLK + r*256 + tid)*10;
    #pragma unroll
    for (int kk=0;kk<10;kk++) a[kk]+=p[kk];
  }
  #pragma unroll
  for (int kk=0;kk<10;kk++){
    float s=a[kk];
    #pragma unroll
    for (int off=1;off<64;off<<=1) s+=__shfl_xor(s,off,64);
    a[kk]=s;
  }
  if (lane==0){
    #pragma unroll
    for (int kk=0;kk<10;kk++) red[w][kk]=a[kk];
  }
  __syncthreads();
  if (tid==0){
    float d[10];
    #pragma unroll
    for (int kk=0;kk<10;kk++) d[kk]=red[0][kk]+red[1][kk]+red[2][kk]+red[3][kk];
    float D[4][4];
    int k2=0;
    #pragma unroll
    for (int i=0;i<4;i++)
      #pragma unroll
      for (int j=i;j<4;j++,k2++){ D[i][j]=d[k2]; D[j][i]=d[k2]; }
    float nrm[4];
    #pragma unroll
    for (int m=0;m<4;m++) nrm[m]=fmaxf(sqrtf(D[m][m]),1e-8f);
    float sc[4];
    #pragma unroll
    for (int i=0;i<4;i++){
      float s=0.f;
      #pragma unroll
      for (int j=0;j<4;j++) s += D[i][j]/(nrm[i]*nrm[j]);
      sc[i] = -(s-1.0f);
    }
    float mx = fmaxf(fmaxf(sc[0],sc[1]), fmaxf(sc[2],sc[3]));
    float e[4], se=0.f;
    #pragma unroll
    for (int m=0;m<4;m++){ e[m]=expf(sc[m]-mx); se+=e[m]; }
    #pragma unroll
    for (int m=0;m<4;m++) probs[b*4+m]=e[m]/se;
  }
}

// GEMM: R27 atomic-free kernel; y-stores reverted to PLAIN stores so y stays
// L2/L3-resident for k_norm's read (NT no-allocate was evicting it to HBM).
__launch_bounds__(256, 2)
__global__ void k_gemm(const float* __restrict__ x, const float* __restrict__ w,
                       const float* __restrict__ ws, float* __restrict__ y,
                       float* __restrict__ part){
  __shared__ float buf[2][SCH][SPX+PAD];
  const int b   = blockIdx.y;
  const int pw  = blockIdx.x * SPX;
  const int tid = threadIdx.x;
  const int wid = tid >> 6;
  const int lane = tid & 63;
  const int l15 = lane & 15;
  const int lg  = lane >> 4;
  const int wr  = wid & 1;      // row half   (32 rows)
  const int wp  = wid >> 1;     // pixel half (128 px)

  const float* probs = ws + 256 + b*4;
  float pm[4] = {probs[0], probs[1], probs[2], probs[3]};
  bhalf8 afrag[2][NCHK];
  const float4* w4 = reinterpret_cast<const float4*>(w);
  #pragma unroll
  for (int rt=0; rt<2; rt++){
    int row = wr*32 + rt*16 + l15;
    #pragma unroll
    for (int ks=0; ks<NCHK; ks++){
      float s = pm[ks>>1];
      float4 a0 = w4[row*64 + ks*8 + lg];
      float4 a1 = w4[row*64 + ks*8 + lg + 4];
      bhalf8 f;
      f[0]=f2bf(a0.x*s); f[1]=f2bf(a0.y*s); f[2]=f2bf(a0.z*s); f[3]=f2bf(a0.w*s);
      f[4]=f2bf(a1.x*s); f[5]=f2bf(a1.y*s); f[6]=f2bf(a1.z*s); f[7]=f2bf(a1.w*s);
      afrag[rt][ks] = f;
    }
  }

  const float* xb = x + (size_t)b*NC*HW + pw;

  auto STAGE = [&](int cc, int cur){
    #pragma unroll
    for (int j=0; j<8; j++){
      int ch_l = wid*8 + j;
      __builtin_amdgcn_global_load_lds(
          (const __attribute__((address_space(1))) void*)(xb + (size_t)(cc*SCH + ch_l)*HW + lane*4),
          (__attribute__((address_space(3))) void*)&buf[cur][ch_l][0],
          16, 0, 0);
    }
  };

  f32x4 acc[2][8];
  #pragma unroll
  for (int rt=0; rt<2; rt++)
    #pragma unroll
    for (int pt=0; pt<8; pt++) acc[rt][pt] = (f32x4){0.f,0.f,0.f,0.f};

  STAGE(0, 0);
  int cur = 0;
  #pragma unroll 1
  for (int cc=0; cc<NCHK; cc++){
    if (cc < NCHK-1){
      STAGE(cc+1, cur^1);
      asm volatile("s_waitcnt vmcnt(8)" ::: "memory");
    } else {
      asm volatile("s_waitcnt vmcnt(0)" ::: "memory");
    }
    __builtin_amdgcn_s_barrier();        // all waves' chunk-cc writes done
    __builtin_amdgcn_sched_barrier(0);

    const float (*bp)[SPX+PAD] = buf[cur];
    #pragma unroll
    for (int pt=0; pt<8; pt++){
      int px_l = wp*128 + pt*16 + l15;
      bhalf8 bfr;
      #pragma unroll
      for (int eh=0; eh<2; eh++)
        #pragma unroll
        for (int el=0; el<4; el++){
          int c_l = lg*4 + el + eh*16;
          bfr[eh*4+el] = f2bf(bp[c_l][px_l]);
        }
      #pragma unroll
      for (int rt=0; rt<2; rt++)
        acc[rt][pt] = __builtin_amdgcn_mfma_f32_16x16x32_bf16(afrag[rt][cc], bfr, acc[rt][pt], 0, 0, 0);
    }

    __builtin_amdgcn_sched_barrier(0);
    __builtin_amdgcn_s_barrier();        // reads done -> buf[cur] reusable
    cur ^= 1;
  }

  // epilogue: PLAIN y write (keep y cache-resident for k_norm) + stats stores
  float sacc[2][4] = {{0}}, qacc[2][4] = {{0}};
  #pragma unroll
  for (int rt=0; rt<2; rt++){
    #pragma unroll
    for (int pt=0; pt<8; pt++){
      size_t ybase = ((size_t)(b*NO + wr*32 + rt*16 + lg*4))*HW + pw + wp*128 + pt*16 + l15;
      #pragma unroll
      for (int r=0; r<4; r++){
        float v = acc[rt][pt][r];
        y[ybase + (size_t)r*HW] = v;
        sacc[rt][r] += v;
        qacc[rt][r] += v*v;
      }
    }
  }
  float* sp = part + ((size_t)(b*64 + blockIdx.x))*NO*4;   // [o][4]: s,q per wp
  #pragma unroll
  for (int rt=0; rt<2; rt++){
    #pragma unroll
    for (int r=0; r<4; r++){
      float s = sacc[rt][r], q = qacc[rt][r];
      #pragma unroll
      for (int off=1; off<16; off<<=1){
        s += __shfl_xor(s, off, 64);
        q += __shfl_xor(q, off, 64);
      }
      if (l15 == 0){
        int o = wr*32 + rt*16 + lg*4 + r;
        sp[o*4 + wp*2]     = s;
        sp[o*4 + wp*2 + 1] = q;
      }
    }
  }
}

__global__ void k_norm(float* __restrict__ y, const float* __restrict__ part){
  __shared__ float red2[2][2];
  const int bo = blockIdx.x, b = bo >> 6, o = bo & 63;
  const int tid = threadIdx.x;
  float s = 0.f, q = 0.f;
  if (tid < 128){
    int bx = tid >> 1, wp = tid & 1;
    const float* p = part + (((size_t)(b*64 + bx))*NO + o)*4 + wp*2;
    s = p[0]; q = p[1];
  }
  #pragma unroll
  for (int off=1; off<64; off<<=1){
    s += __shfl_xor(s, off, 64);
    q += __shfl_xor(q, off, 64);
  }
  if (tid < 128 && (tid & 63) == 0){ red2[tid>>6][0] = s; red2[tid>>6][1] = q; }
  __syncthreads();
  float S = red2[0][0] + red2[1][0];
  float Q = red2[0][1] + red2[1][1];
  float mean = S * (1.f/HW);
  float var  = Q * (1.f/HW) - mean*mean;
  float inv  = rsqrtf(var + EPS_IN);
  f32x4* yp = reinterpret_cast<f32x4*>(y) + (size_t)bo*(HW/4);
  #pragma unroll 4
  for (int i = tid; i < HW/4; i += 256){
    f32x4 v = yp[i];
    v.x = fmaxf((v.x-mean)*inv, 0.f);
    v.y = fmaxf((v.y-mean)*inv, 0.f);
    v.z = fmaxf((v.z-mean)*inv, 0.f);
    v.w = fmaxf((v.w-mean)*inv, 0.f);
    __builtin_nontemporal_store(v, &yp[i]);   // final write: nothing reads y after
  }
}

extern "C" void kernel_launch(void* const* d_in, const int* in_sizes, int n_in,
                              void* d_out, int out_size, void* d_ws, size_t ws_size,
                              hipStream_t stream){
  const float* x = (const float*)d_in[0];
  const float* w = (const float*)d_in[1];
  float* out = (float*)d_out;
  float* ws  = (float*)d_ws;
  float* partials = ws + 8192;
  float* probs    = ws + 256;
  float* part     = ws + 180224;

  k_dots<<<dim3(DBLK,16),    dim3(256), 0, stream>>>(x, partials);
  k_attn<<<dim3(16),         dim3(256), 0, stream>>>(partials, probs);
  k_gemm<<<dim3(HW/SPX,16),  dim3(256), 0, stream>>>(x, w, ws, out, part);
  k_norm<<<dim3(1024),       dim3(256), 0, stream>>>(out, part);
}

// Round 31
// 173.691 us; speedup vs baseline: 1.0055x; 1.0042x over previous
//
#include <hip/hip_runtime.h>
#include <hip/hip_bf16.h>

#define HW 16384
#define NC 256
#define NO 64
#define NPM 1048576          // floats per (b, modality)
#define EPS_IN 1e-5f
#define DBLK 1024            // k_dots blocks.x
#define WIN 1024             // floats per modality per window
#define SPX 256              // pixels per k_gemm block window (R27 geometry)
#define SCH 32               // channels per staged chunk
#define NCHK 8               // 256 / SCH
#define PAD 4                // floats of row padding in LDS

typedef float f32x4 __attribute__((ext_vector_type(4)));
typedef short bhalf8 __attribute__((ext_vector_type(8)));

static __device__ __forceinline__ short f2bf(float f){
  __bf16 h = (__bf16)f;
  return __builtin_bit_cast(short, h);
}

// ws float layout: [256,320) probs[b][m] ; [8192, +163840) dots partials ;
//                  [180224, +262144) gemm stats part[b][bx][o][4]
//                  (all fully overwritten every call -> no zeroing needed)

// Pass 1: Gram partials (proven ~50us / 5.4TB/s structure, untouched).
__global__ void k_dots(const float* __restrict__ x, float* __restrict__ partials){
  __shared__ float lds[4][WIN];
  __shared__ float red[4][16];
  const int b = blockIdx.y, bx = blockIdx.x;
  const int tid = threadIdx.x;
  const int w = tid >> 6, lane = tid & 63;
  const int wi = (bx + b*67) & (DBLK-1);
  const float* src = x + (size_t)b*4*NPM + (size_t)w*NPM + (size_t)wi*WIN + lane*4;

  #pragma unroll
  for (int li=0; li<4; li++){
    __builtin_amdgcn_global_load_lds(
        (const __attribute__((address_space(1))) void*)(src + li*256),
        (__attribute__((address_space(3))) void*)&lds[w][li*256],
        16, 0, 0);
  }
  __syncthreads();

  float4 vv[4];
  #pragma unroll
  for (int m=0;m<4;m++) vv[m] = *(const float4*)&lds[m][tid*4];
  float acc[10];
  int k=0;
  #pragma unroll
  for (int i=0;i<4;i++)
    #pragma unroll
    for (int j=i;j<4;j++,k++)
      acc[k] = vv[i].x*vv[j].x + vv[i].y*vv[j].y + vv[i].z*vv[j].z + vv[i].w*vv[j].w;

  #pragma unroll
  for (int kk=0;kk<10;kk++){
    float s = acc[kk];
    #pragma unroll
    for (int off=1; off<64; off<<=1) s += __shfl_xor(s, off, 64);
    acc[kk]=s;
  }
  if (lane==0){
    #pragma unroll
    for (int kk=0;kk<10;kk++) red[w][kk] = acc[kk];
  }
  __syncthreads();
  if (tid<10){
    float s = red[0][tid] + red[1][tid] + red[2][tid] + red[3][tid];
    partials[((size_t)b*DBLK + bx)*10 + tid] = s;
  }
}

__global__ void k_attn(const float* __restrict__ partials, float* __restrict__ probs){
  __shared__ float red[4][16];
  int b = blockIdx.x, tid = threadIdx.x;       // 256 threads
  int w = tid>>6, lane = tid&63;
  float a[10];
  #pragma unroll
  for (int kk=0;kk<10;kk++) a[kk]=0.f;
  #pragma unroll
  for (int r=0;r<DBLK/256;r++){
    const float* p = partials + ((size_t)b*DBLK + r*256 + tid)*10;
    #pragma unroll
    for (int kk=0;kk<10;kk++) a[kk]+=p[kk];
  }
  #pragma unroll
  for (int kk=0;kk<10;kk++){
    float s=a[kk];
    #pragma unroll
    for (int off=1;off<64;off<<=1) s+=__shfl_xor(s,off,64);
    a[kk]=s;
  }
  if (lane==0){
    #pragma unroll
    for (int kk=0;kk<10;kk++) red[w][kk]=a[kk];
  }
  __syncthreads();
  if (tid==0){
    float d[10];
    #pragma unroll
    for (int kk=0;kk<10;kk++) d[kk]=red[0][kk]+red[1][kk]+red[2][kk]+red[3][kk];
    float D[4][4];
    int k2=0;
    #pragma unroll
    for (int i=0;i<4;i++)
      #pragma unroll
      for (int j=i;j<4;j++,k2++){ D[i][j]=d[k2]; D[j][i]=d[k2]; }
    float nrm[4];
    #pragma unroll
    for (int m=0;m<4;m++) nrm[m]=fmaxf(sqrtf(D[m][m]),1e-8f);
    float sc[4];
    #pragma unroll
    for (int i=0;i<4;i++){
      float s=0.f;
      #pragma unroll
      for (int j=0;j<4;j++) s += D[i][j]/(nrm[i]*nrm[j]);
      sc[i] = -(s-1.0f);
    }
    float mx = fmaxf(fmaxf(sc[0],sc[1]), fmaxf(sc[2],sc[3]));
    float e[4], se=0.f;
    #pragma unroll
    for (int m=0;m<4;m++){ e[m]=expf(sc[m]-mx); se+=e[m]; }
    #pragma unroll
    for (int m=0;m<4;m++) probs[b*4+m]=e[m]/se;
  }
}

// GEMM: R27 best config — atomic-free stats (per-block plain stores to
// private slots), NT y-stores, counted-vmcnt dbuf staging skeleton.
__launch_bounds__(256, 2)
__global__ void k_gemm(const float* __restrict__ x, const float* __restrict__ w,
                       const float* __restrict__ ws, float* __restrict__ y,
                       float* __restrict__ part){
  __shared__ float buf[2][SCH][SPX+PAD];
  const int b   = blockIdx.y;
  const int pw  = blockIdx.x * SPX;
  const int tid = threadIdx.x;
  const int wid = tid >> 6;
  const int lane = tid & 63;
  const int l15 = lane & 15;
  const int lg  = lane >> 4;
  const int wr  = wid & 1;      // row half   (32 rows)
  const int wp  = wid >> 1;     // pixel half (128 px)

  const float* probs = ws + 256 + b*4;
  float pm[4] = {probs[0], probs[1], probs[2], probs[3]};
  bhalf8 afrag[2][NCHK];
  const float4* w4 = reinterpret_cast<const float4*>(w);
  #pragma unroll
  for (int rt=0; rt<2; rt++){
    int row = wr*32 + rt*16 + l15;
    #pragma unroll
    for (int ks=0; ks<NCHK; ks++){
      float s = pm[ks>>1];
      float4 a0 = w4[row*64 + ks*8 + lg];
      float4 a1 = w4[row*64 + ks*8 + lg + 4];
      bhalf8 f;
      f[0]=f2bf(a0.x*s); f[1]=f2bf(a0.y*s); f[2]=f2bf(a0.z*s); f[3]=f2bf(a0.w*s);
      f[4]=f2bf(a1.x*s); f[5]=f2bf(a1.y*s); f[6]=f2bf(a1.z*s); f[7]=f2bf(a1.w*s);
      afrag[rt][ks] = f;
    }
  }

  const float* xb = x + (size_t)b*NC*HW + pw;

  auto STAGE = [&](int cc, int cur){
    #pragma unroll
    for (int j=0; j<8; j++){
      int ch_l = wid*8 + j;
      __builtin_amdgcn_global_load_lds(
          (const __attribute__((address_space(1))) void*)(xb + (size_t)(cc*SCH + ch_l)*HW + lane*4),
          (__attribute__((address_space(3))) void*)&buf[cur][ch_l][0],
          16, 0, 0);
    }
  };

  f32x4 acc[2][8];
  #pragma unroll
  for (int rt=0; rt<2; rt++)
    #pragma unroll
    for (int pt=0; pt<8; pt++) acc[rt][pt] = (f32x4){0.f,0.f,0.f,0.f};

  STAGE(0, 0);
  int cur = 0;
  #pragma unroll 1
  for (int cc=0; cc<NCHK; cc++){
    if (cc < NCHK-1){
      STAGE(cc+1, cur^1);
      asm volatile("s_waitcnt vmcnt(8)" ::: "memory");
    } else {
      asm volatile("s_waitcnt vmcnt(0)" ::: "memory");
    }
    __builtin_amdgcn_s_barrier();        // all waves' chunk-cc writes done
    __builtin_amdgcn_sched_barrier(0);

    const float (*bp)[SPX+PAD] = buf[cur];
    #pragma unroll
    for (int pt=0; pt<8; pt++){
      int px_l = wp*128 + pt*16 + l15;
      bhalf8 bfr;
      #pragma unroll
      for (int eh=0; eh<2; eh++)
        #pragma unroll
        for (int el=0; el<4; el++){
          int c_l = lg*4 + el + eh*16;
          bfr[eh*4+el] = f2bf(bp[c_l][px_l]);
        }
      #pragma unroll
      for (int rt=0; rt<2; rt++)
        acc[rt][pt] = __builtin_amdgcn_mfma_f32_16x16x32_bf16(afrag[rt][cc], bfr, acc[rt][pt], 0, 0, 0);
    }

    __builtin_amdgcn_sched_barrier(0);
    __builtin_amdgcn_s_barrier();        // reads done -> buf[cur] reusable
    cur ^= 1;
  }

  // epilogue: NT y write + per-block stats stores (NO atomics)
  float sacc[2][4] = {{0}}, qacc[2][4] = {{0}};
  #pragma unroll
  for (int rt=0; rt<2; rt++){
    #pragma unroll
    for (int pt=0; pt<8; pt++){
      size_t ybase = ((size_t)(b*NO + wr*32 + rt*16 + lg*4))*HW + pw + wp*128 + pt*16 + l15;
      #pragma unroll
      for (int r=0; r<4; r++){
        float v = acc[rt][pt][r];
        __builtin_nontemporal_store(v, &y[ybase + (size_t)r*HW]);
        sacc[rt][r] += v;
        qacc[rt][r] += v*v;
      }
    }
  }
  float* sp = part + ((size_t)(b*64 + blockIdx.x))*NO*4;   // [o][4]: s,q per wp
  #pragma unroll
  for (int rt=0; rt<2; rt++){
    #pragma unroll
    for (int r=0; r<4; r++){
      float s = sacc[rt][r], q = qacc[rt][r];
      #pragma unroll
      for (int off=1; off<16; off<<=1){
        s += __shfl_xor(s, off, 64);
        q += __shfl_xor(q, off, 64);
      }
      if (l15 == 0){
        int o = wr*32 + rt*16 + lg*4 + r;
        sp[o*4 + wp*2]     = s;
        sp[o*4 + wp*2 + 1] = q;
      }
    }
  }
}

__global__ void k_norm(float* __restrict__ y, const float* __restrict__ part){
  __shared__ float red2[2][2];
  const int bo = blockIdx.x, b = bo >> 6, o = bo & 63;
  const int tid = threadIdx.x;
  float s = 0.f, q = 0.f;
  if (tid < 128){
    int bx = tid >> 1, wp = tid & 1;
    const float* p = part + (((size_t)(b*64 + bx))*NO + o)*4 + wp*2;
    s = p[0]; q = p[1];
  }
  #pragma unroll
  for (int off=1; off<64; off<<=1){
    s += __shfl_xor(s, off, 64);
    q += __shfl_xor(q, off, 64);
  }
  if (tid < 128 && (tid & 63) == 0){ red2[tid>>6][0] = s; red2[tid>>6][1] = q; }
  __syncthreads();
  float S = red2[0][0] + red2[1][0];
  float Q = red2[0][1] + red2[1][1];
  float mean = S * (1.f/HW);
  float var  = Q * (1.f/HW) - mean*mean;
  float inv  = rsqrtf(var + EPS_IN);
  f32x4* yp = reinterpret_cast<f32x4*>(y) + (size_t)bo*(HW/4);
  #pragma unroll 4
  for (int i = tid; i < HW/4; i += 256){
    f32x4 v = yp[i];
    v.x = fmaxf((v.x-mean)*inv, 0.f);
    v.y = fmaxf((v.y-mean)*inv, 0.f);
    v.z = fmaxf((v.z-mean)*inv, 0.f);
    v.w = fmaxf((v.w-mean)*inv, 0.f);
    __builtin_nontemporal_store(v, &yp[i]);
  }
}

extern "C" void kernel_launch(void* const* d_in, const int* in_sizes, int n_in,
                              void* d_out, int out_size, void* d_ws, size_t ws_size,
                              hipStream_t stream){
  const float* x = (const float*)d_in[0];
  const float* w = (const float*)d_in[1];
  float* out = (float*)d_out;
  float* ws  = (float*)d_ws;
  float* partials = ws + 8192;
  float* probs    = ws + 256;
  float* part     = ws + 180224;

  k_dots<<<dim3(DBLK,16),    dim3(256), 0, stream>>>(x, partials);
  k_attn<<<dim3(16),         dim3(256), 0, stream>>>(partials, probs);
  k_gemm<<<dim3(HW/SPX,16),  dim3(256), 0, stream>>>(x, w, ws, out, part);
  k_norm<<<dim3(1024),       dim3(256), 0, stream>>>(out, part);
}